// Round 7
// baseline (226.624 us; speedup 1.0000x reference)
//
#include <hip/hip_runtime.h>
#include <hip/hip_bf16.h>

typedef __attribute__((ext_vector_type(8))) short s8;
typedef __attribute__((ext_vector_type(4))) short s4;
typedef __attribute__((ext_vector_type(4))) float f4;
typedef unsigned short u16;

__device__ __forceinline__ u16 f2bf(float f){
  union { float f; unsigned int i; } v; v.f = f;
  unsigned int x = v.i;
  return (u16)((x + 0x7fffu + ((x >> 16) & 1u)) >> 16);
}
__device__ __forceinline__ unsigned pk2bf(float a, float b){
  __hip_bfloat162 h = __float22bfloat162_rn(float2{a, b});
  union { __hip_bfloat162 h; unsigned u; } c; c.h = h; return c.u;
}
__device__ __forceinline__ s8 ld8(const u16* p){
  return *reinterpret_cast<const s8*>(p);
}
// async global->LDS, 16B/lane; LDS dest = wave-uniform base + lane*16.
__device__ __forceinline__ void async16(const u16* g, u16* l){
  __builtin_amdgcn_global_load_lds(
      (const __attribute__((address_space(1))) unsigned int*)(g),
      (__attribute__((address_space(3))) unsigned int*)(l),
      16, 0, 0);
}

#define MFMA16(a, b, c) __builtin_amdgcn_mfma_f32_16x16x32_bf16((a), (b), (c), 0, 0, 0)

// ---------------------------------------------------------------------------
// prep: (a) W_Q/K/V per-head transposes -> Wt[3072][1024], (b) W_O transpose,
// (c) fp32->bf16 cvt of the 3 X inputs.  (unchanged from r6)
// ---------------------------------------------------------------------------
__global__ __launch_bounds__(256) void prep(
    const float* __restrict__ wq, const float* __restrict__ wk, const float* __restrict__ wv,
    const float* __restrict__ wo,
    const float* __restrict__ x0, const float* __restrict__ x1, const float* __restrict__ x2,
    u16* __restrict__ Wt, u16* __restrict__ Wto, u16* __restrict__ Xb)
{
  __shared__ __align__(16) u16 tile[64 * 65];
  const int id = blockIdx.x, t = threadIdx.x;
  if (id < 768) {
    const int mat = id >> 8, rem = id & 255, h = rem >> 4, kt = rem & 15;
    const float* W = mat == 0 ? wq : (mat == 1 ? wk : wv);
    const float* src = W + (size_t)h * 65536;                    // [1024][64]
    u16* dst = Wt + (size_t)mat * 1048576 + (size_t)h * 65536;   // [64][1024]
    const int k0 = kt * 64;
    #pragma unroll
    for (int i = 0; i < 16; ++i) {
      int idx = i * 256 + t, kr = idx >> 6, d = idx & 63;
      tile[kr * 65 + d] = f2bf(src[(size_t)(k0 + kr) * 64 + d]);
    }
    __syncthreads();
    #pragma unroll
    for (int i = 0; i < 16; ++i) {
      int idx = i * 256 + t, d = idx >> 6, kr = idx & 63;
      dst[(size_t)d * 1024 + k0 + kr] = tile[kr * 65 + d];
    }
  } else if (id < 1024) {
    const int j = id - 768, r0 = (j >> 4) * 64, c0 = (j & 15) * 64;
    #pragma unroll
    for (int i = 0; i < 16; ++i) {
      int idx = i * 256 + t, rr = idx >> 6, cc = idx & 63;
      tile[rr * 65 + cc] = f2bf(wo[(size_t)(r0 + rr) * 1024 + c0 + cc]);
    }
    __syncthreads();
    #pragma unroll
    for (int i = 0; i < 16; ++i) {
      int idx = i * 256 + t, cc = idx >> 6, rr = idx & 63;
      Wto[(size_t)(c0 + cc) * 1024 + r0 + rr] = tile[rr * 65 + cc];
    }
  } else {
    const int j = id - 1024, m = j >> 11, xi = j & 2047;
    const float* src = m == 0 ? x0 : (m == 1 ? x1 : x2);
    u16* d = Xb + (size_t)m * 4194304;
    const size_t i = ((size_t)xi * 256 + t) * 8;
    const float4 a = *reinterpret_cast<const float4*>(src + i);
    const float4 b = *reinterpret_cast<const float4*>(src + i + 4);
    s8 o;
    o[0] = (short)f2bf(a.x); o[1] = (short)f2bf(a.y);
    o[2] = (short)f2bf(a.z); o[3] = (short)f2bf(a.w);
    o[4] = (short)f2bf(b.x); o[5] = (short)f2bf(b.y);
    o[6] = (short)f2bf(b.z); o[7] = (short)f2bf(b.w);
    *reinterpret_cast<s8*>(d + i) = o;
  }
}

// ---------------------------------------------------------------------------
// m97-shape GEMM core (unchanged from r6): 128x128 tile, BK=64,
// global_load_lds staging with XOR-block swizzle in the global src address.
// ---------------------------------------------------------------------------
#define GEMM_CORE(Aptr, Bptr)                                                  \
  f4 acc[4][4] = {};                                                           \
  {                                                                            \
    const int sr8 = lane >> 3;                                                 \
    const int sblk = (lane & 7) ^ sr8;                                         \
    const u16* pa = (Aptr) + (size_t)(wave * 32 + sr8) * 1024 + sblk * 8;      \
    const u16* pb = (Bptr) + (size_t)(wave * 32 + sr8) * 1024 + sblk * 8;      \
    u16* la = &AL[wave * 2048];                                                \
    u16* lb = &BL[wave * 2048];                                                \
    const int e = lm & 7;                                                      \
    for (int k0 = 0; k0 < 1024; k0 += 64) {                                    \
      _Pragma("unroll")                                                        \
      for (int j = 0; j < 4; ++j) {                                            \
        async16(pa + (size_t)j * 8192 + k0, la + j * 512);                     \
        async16(pb + (size_t)j * 8192 + k0, lb + j * 512);                     \
      }                                                                        \
      __syncthreads();                                                         \
      _Pragma("unroll")                                                        \
      for (int kb = 0; kb < 2; ++kb) {                                         \
        s8 af[4], bf[4];                                                       \
        _Pragma("unroll")                                                      \
        for (int i = 0; i < 4; ++i) {                                          \
          af[i] = ld8(&AL[(wm + i * 16 + lm) * 64 + (((kb * 4 + quad) ^ e) * 8)]); \
          bf[i] = ld8(&BL[(wn + i * 16 + lm) * 64 + (((kb * 4 + quad) ^ e) * 8)]); \
        }                                                                      \
        _Pragma("unroll")                                                      \
        for (int mt = 0; mt < 4; ++mt)                                         \
          _Pragma("unroll")                                                    \
          for (int nt = 0; nt < 4; ++nt)                                       \
            acc[mt][nt] = MFMA16(af[mt], bf[nt], acc[mt][nt]);                 \
      }                                                                        \
      __syncthreads();                                                         \
    }                                                                          \
  }

// QKV as one 4096x3072x1024 GEMM; N-block selects (proj, head); V transposed.
__global__ __launch_bounds__(256, 2) void qkv_gemm(
    const u16* __restrict__ Xb, const u16* __restrict__ Wt,
    const float* __restrict__ bq, const float* __restrict__ bk, const float* __restrict__ bv,
    u16* __restrict__ Qo, u16* __restrict__ Ko, u16* __restrict__ Vto)
{
  __shared__ __align__(16) u16 AL[128 * 64];
  __shared__ __align__(16) u16 BL[128 * 64];
  const int tM = blockIdx.x, tN = blockIdx.y;
  const int proj = (tN * 128) >> 10;           // uniform per WG
  const u16* A = Xb + (size_t)proj * 4194304 + (size_t)tM * 131072;
  const u16* B = Wt + (size_t)tN * 131072;
  const int t = threadIdx.x, wave = t >> 6, lane = t & 63;
  const int lm = lane & 15, quad = lane >> 4;
  const int wm = (wave & 1) * 64, wn = (wave >> 1) * 64;
  GEMM_CORE(A, B)
  const int mb = tM * 128 + wm;
  const int nb = tN * 128 + wn;
  if (proj < 2) {
    u16* O = proj == 0 ? Qo : Ko;
    const float* bi = proj == 0 ? bq : bk;
    #pragma unroll
    for (int nt = 0; nt < 4; ++nt) {
      const int nl = (nb + nt * 16 + lm) & 1023;
      const int h = nl >> 6, d = nl & 63;
      const float bb = bi[nl];
      #pragma unroll
      for (int mt = 0; mt < 4; ++mt) {
        const int m = mb + mt * 16 + quad * 4;
        const size_t base = ((size_t)((m >> 11) * 16 + h) * 2048 + (m & 2047)) * 64 + d;
        #pragma unroll
        for (int r = 0; r < 4; ++r)
          O[base + (size_t)r * 64] = f2bf(acc[mt][nt][r] + bb);
      }
    }
  } else {
    #pragma unroll
    for (int nt = 0; nt < 4; ++nt) {
      const int nl = (nb + nt * 16 + lm) & 1023;
      const int h = nl >> 6, d = nl & 63;
      const float bb = bv[nl];
      #pragma unroll
      for (int mt = 0; mt < 4; ++mt) {
        const int m = mb + mt * 16 + quad * 4;
        s4 pk;
        #pragma unroll
        for (int r = 0; r < 4; ++r) pk[r] = (short)f2bf(acc[mt][nt][r] + bb);
        *reinterpret_cast<s4*>(
            Vto + ((size_t)((m >> 11) * 16 + h) * 64 + d) * 2048 + (m & 2047)) = pk;
      }
    }
  }
}

// Output projection: Z[4096][1024] x Wto[1024n][1024k] + bO -> fp32 out.
__global__ __launch_bounds__(256, 2) void out_gemm(
    const u16* __restrict__ Zi, const u16* __restrict__ Wto,
    const float* __restrict__ bO, float* __restrict__ Out)
{
  __shared__ __align__(16) u16 AL[128 * 64];
  __shared__ __align__(16) u16 BL[128 * 64];
  const int tM = blockIdx.x, tN = blockIdx.y;
  const u16* A = Zi + (size_t)tM * 131072;
  const u16* B = Wto + (size_t)tN * 131072;
  const int t = threadIdx.x, wave = t >> 6, lane = t & 63;
  const int lm = lane & 15, quad = lane >> 4;
  const int wm = (wave & 1) * 64, wn = (wave >> 1) * 64;
  GEMM_CORE(A, B)
  const int mb = tM * 128 + wm;
  const int nb = tN * 128 + wn;
  #pragma unroll
  for (int nt = 0; nt < 4; ++nt) {
    const int n = nb + nt * 16 + lm;
    const float bb = bO[n];
    #pragma unroll
    for (int mt = 0; mt < 4; ++mt) {
      const int m = mb + mt * 16 + quad * 4;
      #pragma unroll
      for (int r = 0; r < 4; ++r)
        Out[(size_t)(m + r) * 1024 + n] = acc[mt][nt][r] + bb;
    }
  }
}

// ---------------------------------------------------------------------------
// Flash attention v6:
//  - WG pairing: each WG handles q-chunks (31-j) then (j) -> exactly 33
//    k-tiles per WG; grid 512 = 2 WGs/CU, uniform makespan.
//  - BK=128: two 64-key sub-tiles staged per barrier round (half the
//    barriers), computed in wide phases (16 QK MFMA -> 32 exp2 -> P stores ->
//    fence -> 16 PV MFMA) for cross-sub-tile ILP.
//  - LDS = 32K (K dbuf) + 32K (V dbuf) + 16K (P) = 80 KB -> 2 WGs/CU.
//  - launch_bounds(256,2): VGPR cap 256 (r6's cap-128 gave VGPR=52 and a
//    serialized pipeline).
// ---------------------------------------------------------------------------
__device__ __forceinline__ void qk_scores(const u16* Kc, s8 bQ0, s8 bQ1,
                                          int fb0, int fb1, f4 sc[4])
{
  #pragma unroll
  for (int nt = 0; nt < 4; ++nt) {
    sc[nt] = MFMA16(ld8(Kc + fb0 + nt * 1024), bQ0, sc[nt]);
    sc[nt] = MFMA16(ld8(Kc + fb1 + nt * 1024), bQ1, sc[nt]);
  }
}

__device__ __forceinline__ float softmax_p(const f4 sc[4], int k0, bool masked,
                                           int q, const float* __restrict__ mk,
                                           u16* Pp, int lm, int quad, int e)
{
  const float SC = 0.125f * 1.44269504f;      // 1/sqrt(64) * log2(e)
  float psum = 0.f;
  #pragma unroll
  for (int nt = 0; nt < 4; ++nt) {
    const int key0 = k0 + nt * 16 + quad * 4;
    const float4 mv = *reinterpret_cast<const float4*>(mk + key0);
    float p[4];
    if (masked) {
      #pragma unroll
      for (int r = 0; r < 4; ++r) {
        float s = (key0 + r <= q)
                  ? sc[nt][r] * SC + (&mv.x)[r] * 1.44269504f
                  : -__builtin_inff();
        p[r] = exp2f(s);
      }
    } else {
      #pragma unroll
      for (int r = 0; r < 4; ++r)
        p[r] = exp2f(sc[nt][r] * SC + (&mv.x)[r] * 1.44269504f);
    }
    psum += (p[0] + p[1]) + (p[2] + p[3]);
    const int wblk = (nt * 2 + (quad >> 1)) ^ e;
    *reinterpret_cast<uint2*>(&Pp[lm * 64 + wblk * 8 + (quad & 1) * 4]) =
        uint2{pk2bf(p[0], p[1]), pk2bf(p[2], p[3])};
  }
  return psum;
}

__device__ __forceinline__ void pv_acc(const u16* Vc, const u16* Pp,
                                       int fb0, int fb1, int lm, int quad,
                                       int e, f4 o[4])
{
  #pragma unroll
  for (int kb = 0; kb < 2; ++kb) {
    const int rblk = (kb * 4 + quad) ^ e;
    s8 bP = ld8(&Pp[lm * 64 + rblk * 8]);
    const int fb = kb ? fb1 : fb0;
    #pragma unroll
    for (int nt = 0; nt < 4; ++nt)
      o[nt] = MFMA16(ld8(Vc + fb + nt * 1024), bP, o[nt]);
  }
}

__global__ __launch_bounds__(256, 2) void attn(
    const u16* __restrict__ Q, const u16* __restrict__ K, const u16* __restrict__ Vt,
    const float* __restrict__ amask, u16* __restrict__ Z)
{
  __shared__ __align__(16) u16 KL[2][8192];
  __shared__ __align__(16) u16 VL[2][8192];
  __shared__ __align__(16) u16 Pl[4][2048];
  const int wg   = blockIdx.x;
  const int xcd  = wg & 7, rest = wg >> 3;
  const int bhl  = rest & 3, j = rest >> 2;   // j in 0..15
  const int bh   = xcd * 4 + bhl;
  const int b    = bh >> 4, h = bh & 15;
  const int t = threadIdx.x, wave = t >> 6, lane = t & 63;
  const int lm = lane & 15, quad = lane >> 4;
  const u16* Qb = Q + (size_t)bh * 131072;
  const u16* Kb = K + (size_t)bh * 131072;
  const u16* Vb = Vt + (size_t)bh * 131072;
  const float* mk = amask + b * 2048;
  u16* PwA = Pl[wave];
  u16* PwB = Pl[wave] + 1024;

  // staging lane decomposition (per 8-row chunk): row lr, swizzled src block
  const int lr = lane >> 3;
  const int sw = (lane & 7) ^ lr;
  // fragment read offsets: row*64 + ((blk)^(row&7))*8
  const int e = lm & 7;
  const int fb0 = lm * 64 + ((quad ^ e) * 8);
  const int fb1 = lm * 64 + (((4 + quad) ^ e) * 8);

  #pragma unroll 1
  for (int half = 0; half < 2; ++half) {
    const int qc = half == 0 ? 31 - j : j;
    const int nT = qc + 1, nFull = nT >> 1, nPairs = (nT + 1) >> 1;
    const int q = qc * 64 + wave * 16 + lm;   // this lane's query column
    const s8 bQ0 = ld8(Qb + (size_t)q * 64 + quad * 8);
    const s8 bQ1 = ld8(Qb + (size_t)q * 64 + 32 + quad * 8);
    f4 o[4] = {f4{0,0,0,0}, f4{0,0,0,0}, f4{0,0,0,0}, f4{0,0,0,0}};
    float psum = 0.f;

    __syncthreads();                          // buffers free from prior half
    // prologue: stage pair 0 into buffer 0 (K: 4 async16, V: 4 async16)
    {
      const u16* gk = Kb + (size_t)(16 * wave + lr) * 64 + sw * 8;
      u16* kd = KL[0] + 1024 * wave;
      async16(gk, kd);                async16(gk + 512, kd + 512);
      async16(gk + 4096, kd + 4096);  async16(gk + 4608, kd + 4608);
      const u16* gv = Vb + (size_t)(16 * wave + lr) * 2048 + sw * 8;
      u16* vd = VL[0] + 1024 * wave;
      async16(gv, vd);                 async16(gv + 16384, vd + 512);
      async16(gv + 64, vd + 4096);     async16(gv + 16448, vd + 4608);
    }

    for (int it = 0; it < nFull; ++it) {
      __syncthreads();                        // publishes buf(it&1)
      if (it + 1 < nPairs) {                  // stage pair it+1 under compute
        const int p2 = (it + 1) & 1;
        const int kb0 = (it + 1) * 128;
        const u16* gk = Kb + (size_t)(kb0 + 16 * wave + lr) * 64 + sw * 8;
        u16* kd = KL[p2] + 1024 * wave;
        async16(gk, kd);                async16(gk + 512, kd + 512);
        async16(gk + 4096, kd + 4096);  async16(gk + 4608, kd + 4608);
        const u16* gv = Vb + (size_t)(16 * wave + lr) * 2048 + kb0 + sw * 8;
        u16* vd = VL[p2] + 1024 * wave;
        async16(gv, vd);                 async16(gv + 16384, vd + 512);
        async16(gv + 64, vd + 4096);     async16(gv + 16448, vd + 4608);
      }
      const u16* Kc = KL[it & 1];
      const u16* Vc = VL[it & 1];
      const int k0 = it * 128;
      const bool mB = (it == nFull - 1) && !(nT & 1);
      f4 s0[4] = {f4{0,0,0,0}, f4{0,0,0,0}, f4{0,0,0,0}, f4{0,0,0,0}};
      f4 s1[4] = {f4{0,0,0,0}, f4{0,0,0,0}, f4{0,0,0,0}, f4{0,0,0,0}};
      qk_scores(Kc,        bQ0, bQ1, fb0, fb1, s0);
      qk_scores(Kc + 4096, bQ0, bQ1, fb0, fb1, s1);
      psum += softmax_p(s0, k0,      false, q, mk, PwA, lm, quad, e);
      psum += softmax_p(s1, k0 + 64, mB,    q, mk, PwB, lm, quad, e);
      __asm__ volatile("" ::: "memory");      // P writes before P reads
      pv_acc(Vc,        PwA, fb0, fb1, lm, quad, e, o);
      pv_acc(Vc + 4096, PwB, fb0, fb1, lm, quad, e, o);
      __asm__ volatile("" ::: "memory");      // P reads before next writes
    }
    if (nT & 1) {                             // trailing single (masked) tile
      __syncthreads();
      const u16* Kc = KL[nFull & 1];
      const u16* Vc = VL[nFull & 1];
      const int k0 = nFull * 128;
      f4 s0[4] = {f4{0,0,0,0}, f4{0,0,0,0}, f4{0,0,0,0}, f4{0,0,0,0}};
      qk_scores(Kc, bQ0, bQ1, fb0, fb1, s0);
      psum += softmax_p(s0, k0, true, q, mk, PwA, lm, quad, e);
      __asm__ volatile("" ::: "memory");
      pv_acc(Vc, PwA, fb0, fb1, lm, quad, e, o);
      __asm__ volatile("" ::: "memory");
    }

    psum += __shfl_xor(psum, 16, 64);
    psum += __shfl_xor(psum, 32, 64);
    const float inv = 1.0f / psum;
    u16* zr = Z + (size_t)(b * 2048 + q) * 1024 + h * 64;
    #pragma unroll
    for (int nt = 0; nt < 4; ++nt) {
      s4 pk;
      #pragma unroll
      for (int r = 0; r < 4; ++r) pk[r] = (short)f2bf(o[nt][r] * inv);
      *reinterpret_cast<s4*>(zr + nt * 16 + quad * 4) = pk;
    }
  }
}

// ---------------------------------------------------------------------------
extern "C" void kernel_launch(void* const* d_in, const int* in_sizes, int n_in,
                              void* d_out, int out_size, void* d_ws, size_t ws_size,
                              hipStream_t stream)
{
  const float* xq = (const float*)d_in[0];
  const float* xk = (const float*)d_in[1];
  const float* xv = (const float*)d_in[2];
  const float* am = (const float*)d_in[3];
  const float* wq = (const float*)d_in[4];
  const float* wk = (const float*)d_in[5];
  const float* wv = (const float*)d_in[6];
  const float* wo = (const float*)d_in[7];
  const float* bq = (const float*)d_in[8];
  const float* bk = (const float*)d_in[9];
  const float* bv = (const float*)d_in[10];
  const float* bo = (const float*)d_in[11];
  u16* ws = (u16*)d_ws;
  const size_t M1 = 1u << 20;
  u16* Wt  = ws;              // [3072][1024] bf16 (Wq,Wk,Wv stacked)
  u16* Wto = ws + 3 * M1;     // [1024][1024] bf16
  u16* Xb  = ws + 4 * M1;     // 3 x [4096][1024] bf16
  u16* Qw  = ws + 16 * M1;    // [2][16][2048][64] bf16
  u16* Kw  = ws + 20 * M1;    // [2][16][2048][64] bf16
  u16* Vtw = ws + 24 * M1;    // [2][16][64][2048] bf16
  u16* Zw  = ws + 28 * M1;    // [4096][1024] bf16

  prep<<<dim3(7168), 256, 0, stream>>>(wq, wk, wv, wo, xq, xk, xv, Wt, Wto, Xb);
  qkv_gemm<<<dim3(32, 24), 256, 0, stream>>>(Xb, Wt, bq, bk, bv, Qw, Kw, Vtw);
  attn<<<dim3(512), 256, 0, stream>>>(Qw, Kw, Vtw, am, Zw);
  out_gemm<<<dim3(32, 8), 256, 0, stream>>>(Zw, Wto, bo, (float*)d_out);
}